// Round 5
// baseline (1726.467 us; speedup 1.0000x reference)
//
#include <hip/hip_runtime.h>

// Persistent LSTM: N=4096, T=256, IN=2, E=64, H=128, OUT=2.
// 512 blocks x 512 threads (8 waves); block b owns batch rows [8b, 8b+8).
// 2 blocks/CU co-resident (VGPR<=128 forced, LDS ~50KB) -> 4 waves/SIMD with
// INDEPENDENT barriers: two step-chains interleave per SIMD (latency hiding
// that round-2's single resident block could not get).
// Gates [8(pad16),512] = [embed|h][8,192] @ B[192,512] via mfma 16x16x32 bf16.
// Wave w owns gate columns (gate g, unit 16w+l15); EW is register-local on
// half-wave (lq<2). A-buffer rows 8-15 zeroed once. 2-buffer ping-pong,
// 1 barrier/step. y-proj = 4 extra MFMAs on wave 0 (fy frags from LDS).

#define T_LEN 256
#define ASTR  200

typedef __attribute__((ext_vector_type(8))) short short8;
typedef __attribute__((ext_vector_type(4))) float f32x4;
typedef __attribute__((ext_vector_type(2))) float f32x2;

__device__ __forceinline__ unsigned short f2bf(float f) {
  unsigned u = __builtin_bit_cast(unsigned, f);
  u += 0x7fffu + ((u >> 16) & 1u);           // RNE
  return (unsigned short)(u >> 16);
}
__device__ __forceinline__ f32x2 exp2v(f32x2 x) {
  return (f32x2){__builtin_amdgcn_exp2f(x[0]), __builtin_amdgcn_exp2f(x[1])};
}
__device__ __forceinline__ f32x2 rcpv(f32x2 x) {
  return (f32x2){__builtin_amdgcn_rcpf(x[0]), __builtin_amdgcn_rcpf(x[1])};
}

// fused LSTM cell on 2 rows: sig(x)=1/(1+2^(K1 x)), tanh=(1-2^(K2 x))/(1+2^(K2 x))
__device__ __forceinline__ f32x2 ewpair(f32x2 i, f32x2 f, f32x2 g, f32x2 o, f32x2& c) {
  const float K1 = -1.4426950408889634f, K2 = -2.8853900817779268f;
  f32x2 ei = exp2v(i * K1);
  f32x2 ef = exp2v(f * K1);
  f32x2 eg = exp2v(g * K2);
  f32x2 eo = exp2v(o * K1);
  f32x2 t1 = ei + 1.f, tf = ef + 1.f, t2 = eg + 1.f, t3 = 1.f - eg, to = eo + 1.f;
  f32x2 q1 = t1 * t2;
  f32x2 num = c * q1 + t3 * tf;
  f32x2 cn = num * rcpv(q1 * tf);
  c = cn;
  f32x2 cc = __builtin_elementwise_min(
      __builtin_elementwise_max(cn, (f32x2){-20.f, -20.f}), (f32x2){20.f, 20.f});
  f32x2 ec = exp2v(cc * K2);
  return (1.f - ec) * rcpv(to * (ec + 1.f));
}

__device__ __forceinline__ short8 packbf8(const float* src) {
  float4 lo = *(const float4*)src;
  float4 hi = *(const float4*)(src + 4);
  short8 f;
  f[0] = (short)f2bf(lo.x); f[1] = (short)f2bf(lo.y);
  f[2] = (short)f2bf(lo.z); f[3] = (short)f2bf(lo.w);
  f[4] = (short)f2bf(hi.x); f[5] = (short)f2bf(hi.y);
  f[6] = (short)f2bf(hi.z); f[7] = (short)f2bf(hi.w);
  return f;
}

#define MFMA __builtin_amdgcn_mfma_f32_16x16x32_bf16

__global__ __launch_bounds__(512, 4) void lstm_persist(
    const float* __restrict__ x,    const float* __restrict__ W_in,
    const float* __restrict__ b_in, const float* __restrict__ W_ih,
    const float* __restrict__ W_hh, const float* __restrict__ b_ih,
    const float* __restrict__ b_hh, const float* __restrict__ W_out,
    const float* __restrict__ b_out, float* __restrict__ out)
{
  __shared__ __align__(16) float xsT[2 * T_LEN][16];            // 32 KB (rows 0-7 used)
  __shared__ __align__(16) unsigned short Abuf[2][16][ASTR];    // 12.5 KB ping-pong
  __shared__ __align__(16) unsigned short fyB[4 * 64 * 8];      // 4 KB y-proj frags
  __shared__ float WinS[128];
  __shared__ float binS[64];

  const int tid = threadIdx.x;
  const int w   = tid >> 6;
  const int l   = tid & 63;
  const int l15 = l & 15;
  const int lq  = l >> 4;
  const int u   = w * 16 + l15;

  // ---- stage x (8 rows x 512 floats), transposed ----
  const float* xg = x + (size_t)blockIdx.x * (8 * 2 * T_LEN);
  #pragma unroll
  for (int i = tid; i < 1024; i += 512) {
    float4 v = ((const float4*)xg)[i];
    int fi = i * 4, r = fi >> 9, c0 = fi & 511;
    xsT[c0][r] = v.x; xsT[c0 + 1][r] = v.y; xsT[c0 + 2][r] = v.z; xsT[c0 + 3][r] = v.w;
  }
  if (tid < 128) WinS[tid] = W_in[tid];
  if (tid < 64)  binS[tid] = b_in[tid];

  // ---- gate weight fragments (96 VGPR) + scalar bias ----
  short8 fb[4][6];
  float  bias[4];
  #pragma unroll
  for (int g = 0; g < 4; ++g) {
    const int grow = g * 128 + u;
    bias[g] = b_ih[grow] + b_hh[grow];
    #pragma unroll
    for (int kt = 0; kt < 6; ++kt) {
      const int kk = kt * 32 + lq * 8;
      const float* src = (kk < 64) ? (W_ih + grow * 64 + kk)
                                   : (W_hh + grow * 128 + (kk - 64));
      fb[g][kt] = packbf8(src);
    }
  }
  // y-proj fragments -> LDS (wave 0 loads)
  if (w == 0) {
    #pragma unroll
    for (int kt = 0; kt < 4; ++kt) {
      short8 fy = {0, 0, 0, 0, 0, 0, 0, 0};
      if (l15 < 2) fy = packbf8(W_out + l15 * 128 + kt * 32 + lq * 8);
      *(short8*)&fyB[(kt * 64 + l) * 8] = fy;
    }
  }
  const float bout_r = (l15 < 2) ? b_out[l15] : 0.f;

  __syncthreads();   // xsT, WinS, binS, fyB ready

  // ---- zero pad rows 8-15 of both buffers (full ASTR) ----
  for (int j = tid; j < 1600; j += 512) {
    const int buf = j / 800, rem = j % 800;
    const int r = 8 + rem / 100, c = (rem % 100) * 2;
    *(unsigned*)&Abuf[buf][r][c] = 0u;
  }
  // zero h-region rows 0-7 of buf0 (512 u32)
  if (tid < 512) {
    const int r = tid >> 6;
    ((unsigned*)&Abuf[0][r][64])[tid & 63] = 0u;
  }
  // embed e0 -> buf0 (1 value/thread: wave w handles row w)
  {
    const int r = w, e = l;
    const float x0 = xsT[0][r], x1 = xsT[1][r];
    float v = fmaf(x1, WinS[2 * e + 1], fmaf(x0, WinS[2 * e], binS[e]));
    Abuf[0][r][e] = f2bf(v > 0.f ? v : 0.f);
  }
  __syncthreads();

  f32x2 c01 = {0.f, 0.f}, c23 = {0.f, 0.f};
  const size_t obase = (size_t)blockIdx.x * (8 * 2 * T_LEN);
  const int yrow = (lq & 1) * 4;   // clamped row base for y residual reads

  for (int t = 0; t < T_LEN; ++t) {
    const int p = t & 1;
    const unsigned short (*bR)[ASTR] = Abuf[p];
    unsigned short (*bW)[ASTR] = Abuf[p ^ 1];

    // A fragments (6 k-tiles)
    short8 a0 = *(const short8*)&bR[l15][0 * 32 + lq * 8];
    short8 a1 = *(const short8*)&bR[l15][1 * 32 + lq * 8];
    short8 a2 = *(const short8*)&bR[l15][2 * 32 + lq * 8];
    short8 a3 = *(const short8*)&bR[l15][3 * 32 + lq * 8];
    short8 a4 = *(const short8*)&bR[l15][4 * 32 + lq * 8];
    short8 a5 = *(const short8*)&bR[l15][5 * 32 + lq * 8];

    f32x4 acc[4];
    #pragma unroll
    for (int g = 0; g < 4; ++g) {
      f32x4 s = (f32x4){bias[g], bias[g], bias[g], bias[g]};
      s = MFMA(a0, fb[g][0], s, 0, 0, 0);
      s = MFMA(a1, fb[g][1], s, 0, 0, 0);
      s = MFMA(a2, fb[g][2], s, 0, 0, 0);
      s = MFMA(a3, fb[g][3], s, 0, 0, 0);
      s = MFMA(a4, fb[g][4], s, 0, 0, 0);
      s = MFMA(a5, fb[g][5], s, 0, 0, 0);
      acc[g] = s;
    }

    // y_{t-1} = h_t @ W_out^T + b_out + x_{t-1}  (wave 0; h_t = a2..a5)
    if (w == 0) {
      const int tt = t ? t - 1 : 0;
      f32x4 accY;
      #pragma unroll
      for (int q = 0; q < 4; ++q)
        accY[q] = (l15 < 2) ? (bout_r + xsT[2 * tt + l15][yrow + q]) : 0.f;
      const short8 fy0 = *(const short8*)&fyB[(0 * 64 + l) * 8];
      const short8 fy1 = *(const short8*)&fyB[(1 * 64 + l) * 8];
      const short8 fy2 = *(const short8*)&fyB[(2 * 64 + l) * 8];
      const short8 fy3 = *(const short8*)&fyB[(3 * 64 + l) * 8];
      accY = MFMA(a2, fy0, accY, 0, 0, 0);
      accY = MFMA(a3, fy1, accY, 0, 0, 0);
      accY = MFMA(a4, fy2, accY, 0, 0, 0);
      accY = MFMA(a5, fy3, accY, 0, 0, 0);
      if (t > 0 && l15 < 2 && lq < 2) {
        #pragma unroll
        for (int q = 0; q < 4; ++q)
          out[obase + (size_t)(lq * 4 + q) * (2 * T_LEN) + 2 * (t - 1) + l15] = accY[q];
      }
    }

    // EW (half-wave: rows 0-7 live on lq<2) -> h_{t+1} into bW
    if (lq < 2) {
      const int row0 = lq * 4;
      {
        f32x2 iv = {acc[0][0], acc[0][1]}, fv = {acc[1][0], acc[1][1]};
        f32x2 gv = {acc[2][0], acc[2][1]}, ov = {acc[3][0], acc[3][1]};
        f32x2 h01 = ewpair(iv, fv, gv, ov, c01);
        bW[row0 + 0][64 + u] = f2bf(h01[0]);
        bW[row0 + 1][64 + u] = f2bf(h01[1]);
      }
      {
        f32x2 iv = {acc[0][2], acc[0][3]}, fv = {acc[1][2], acc[1][3]};
        f32x2 gv = {acc[2][2], acc[2][3]}, ov = {acc[3][2], acc[3][3]};
        f32x2 h23 = ewpair(iv, fv, gv, ov, c23);
        bW[row0 + 2][64 + u] = f2bf(h23[0]);
        bW[row0 + 3][64 + u] = f2bf(h23[1]);
      }
    }

    // embed e_{t+1} -> bW (1 value/thread)
    if (t + 1 < T_LEN) {
      const int r = w, e = l;
      const float x0 = xsT[2 * (t + 1)][r], x1 = xsT[2 * (t + 1) + 1][r];
      float v = fmaf(x1, WinS[2 * e + 1], fmaf(x0, WinS[2 * e], binS[e]));
      bW[r][e] = f2bf(v > 0.f ? v : 0.f);
    }

    __syncthreads();   // ONE barrier per step
  }

  // epilogue: y_255 = h_256 @ W_out^T + b_out + x_255 ; h_256 is in Abuf[0]
  if (w == 0) {
    const unsigned short (*hb)[ASTR] = Abuf[0];
    const short8 a2 = *(const short8*)&hb[l15][2 * 32 + lq * 8];
    const short8 a3 = *(const short8*)&hb[l15][3 * 32 + lq * 8];
    const short8 a4 = *(const short8*)&hb[l15][4 * 32 + lq * 8];
    const short8 a5 = *(const short8*)&hb[l15][5 * 32 + lq * 8];
    f32x4 accY;
    #pragma unroll
    for (int q = 0; q < 4; ++q)
      accY[q] = (l15 < 2) ? (bout_r + xsT[2 * 255 + l15][yrow + q]) : 0.f;
    const short8 fy0 = *(const short8*)&fyB[(0 * 64 + l) * 8];
    const short8 fy1 = *(const short8*)&fyB[(1 * 64 + l) * 8];
    const short8 fy2 = *(const short8*)&fyB[(2 * 64 + l) * 8];
    const short8 fy3 = *(const short8*)&fyB[(3 * 64 + l) * 8];
    accY = MFMA(a2, fy0, accY, 0, 0, 0);
    accY = MFMA(a3, fy1, accY, 0, 0, 0);
    accY = MFMA(a4, fy2, accY, 0, 0, 0);
    accY = MFMA(a5, fy3, accY, 0, 0, 0);
    if (l15 < 2 && lq < 2) {
      #pragma unroll
      for (int q = 0; q < 4; ++q)
        out[obase + (size_t)(lq * 4 + q) * (2 * T_LEN) + 2 * 255 + l15] = accY[q];
    }
  }
}

extern "C" void kernel_launch(void* const* d_in, const int* in_sizes, int n_in,
                              void* d_out, int out_size, void* d_ws, size_t ws_size,
                              hipStream_t stream) {
  const float* x     = (const float*)d_in[0];
  const float* W_in  = (const float*)d_in[1];
  const float* b_in  = (const float*)d_in[2];
  const float* W_ih  = (const float*)d_in[3];
  const float* W_hh  = (const float*)d_in[4];
  const float* b_ih  = (const float*)d_in[5];
  const float* b_hh  = (const float*)d_in[6];
  const float* W_out = (const float*)d_in[7];
  const float* b_out = (const float*)d_in[8];
  float* out = (float*)d_out;

  lstm_persist<<<dim3(512), dim3(512), 0, stream>>>(
      x, W_in, b_in, W_ih, W_hh, b_ih, b_hh, W_out, b_out, out);
}

// Round 6
// 537.681 us; speedup vs baseline: 3.2109x; 3.2109x over previous
//
#include <hip/hip_runtime.h>

// Persistent LSTM: N=4096, T=256, IN=2, E=64, H=128, OUT=2.
// 512 blocks x 512 threads (8 waves); block b owns batch rows [8b, 8b+8).
// __launch_bounds__(512, 2): HIP 2nd arg == min BLOCKS/CU (CUDA semantics,
// verified empirically r5: (512,4)->64 VGPR + 4GB spill traffic; (512,2)->128
// VGPR, no spills). 2 blocks/CU co-reside -> 4 waves/SIMD with INDEPENDENT
// barriers; two step-chains interleave per SIMD.
// Gates [8(pad16),512] = [embed|h][8,192] @ B[192,512] via mfma 16x16x32 bf16.
// Wave w owns gate columns (gate g, unit 16w+l15); EW register-local on lq<2.
// Rows 8-15 of A-buffer zeroed once. 2-buffer ping-pong, 1 barrier/step.
// y-proj = 4 extra MFMAs on wave 0 (fy frags from LDS).

#define T_LEN 256
#define ASTR  200

typedef __attribute__((ext_vector_type(8))) short short8;
typedef __attribute__((ext_vector_type(4))) float f32x4;
typedef __attribute__((ext_vector_type(2))) float f32x2;

__device__ __forceinline__ unsigned short f2bf(float f) {
  unsigned u = __builtin_bit_cast(unsigned, f);
  u += 0x7fffu + ((u >> 16) & 1u);           // RNE
  return (unsigned short)(u >> 16);
}
__device__ __forceinline__ f32x2 exp2v(f32x2 x) {
  return (f32x2){__builtin_amdgcn_exp2f(x[0]), __builtin_amdgcn_exp2f(x[1])};
}
__device__ __forceinline__ f32x2 rcpv(f32x2 x) {
  return (f32x2){__builtin_amdgcn_rcpf(x[0]), __builtin_amdgcn_rcpf(x[1])};
}

// fused LSTM cell on 2 rows: sig(x)=1/(1+2^(K1 x)), tanh=(1-2^(K2 x))/(1+2^(K2 x))
__device__ __forceinline__ f32x2 ewpair(f32x2 i, f32x2 f, f32x2 g, f32x2 o, f32x2& c) {
  const float K1 = -1.4426950408889634f, K2 = -2.8853900817779268f;
  f32x2 ei = exp2v(i * K1);
  f32x2 ef = exp2v(f * K1);
  f32x2 eg = exp2v(g * K2);
  f32x2 eo = exp2v(o * K1);
  f32x2 t1 = ei + 1.f, tf = ef + 1.f, t2 = eg + 1.f, t3 = 1.f - eg, to = eo + 1.f;
  f32x2 q1 = t1 * t2;
  f32x2 num = c * q1 + t3 * tf;
  f32x2 cn = num * rcpv(q1 * tf);
  c = cn;
  f32x2 cc = __builtin_elementwise_min(
      __builtin_elementwise_max(cn, (f32x2){-20.f, -20.f}), (f32x2){20.f, 20.f});
  f32x2 ec = exp2v(cc * K2);
  return (1.f - ec) * rcpv(to * (ec + 1.f));
}

__device__ __forceinline__ short8 packbf8(const float* src) {
  float4 lo = *(const float4*)src;
  float4 hi = *(const float4*)(src + 4);
  short8 f;
  f[0] = (short)f2bf(lo.x); f[1] = (short)f2bf(lo.y);
  f[2] = (short)f2bf(lo.z); f[3] = (short)f2bf(lo.w);
  f[4] = (short)f2bf(hi.x); f[5] = (short)f2bf(hi.y);
  f[6] = (short)f2bf(hi.z); f[7] = (short)f2bf(hi.w);
  return f;
}

#define MFMA __builtin_amdgcn_mfma_f32_16x16x32_bf16

__global__ __launch_bounds__(512, 2) void lstm_persist(
    const float* __restrict__ x,    const float* __restrict__ W_in,
    const float* __restrict__ b_in, const float* __restrict__ W_ih,
    const float* __restrict__ W_hh, const float* __restrict__ b_ih,
    const float* __restrict__ b_hh, const float* __restrict__ W_out,
    const float* __restrict__ b_out, float* __restrict__ out)
{
  __shared__ __align__(16) float xsT[2 * T_LEN][16];            // 32 KB (rows 0-7 used)
  __shared__ __align__(16) unsigned short Abuf[2][16][ASTR];    // 12.5 KB ping-pong
  __shared__ __align__(16) unsigned short fyB[4 * 64 * 8];      // 4 KB y-proj frags
  __shared__ float WinS[128];
  __shared__ float binS[64];

  const int tid = threadIdx.x;
  const int w   = tid >> 6;
  const int l   = tid & 63;
  const int l15 = l & 15;
  const int lq  = l >> 4;
  const int u   = w * 16 + l15;

  // ---- stage x (8 rows x 512 floats), transposed ----
  const float* xg = x + (size_t)blockIdx.x * (8 * 2 * T_LEN);
  #pragma unroll
  for (int i = tid; i < 1024; i += 512) {
    float4 v = ((const float4*)xg)[i];
    int fi = i * 4, r = fi >> 9, c0 = fi & 511;
    xsT[c0][r] = v.x; xsT[c0 + 1][r] = v.y; xsT[c0 + 2][r] = v.z; xsT[c0 + 3][r] = v.w;
  }
  if (tid < 128) WinS[tid] = W_in[tid];
  if (tid < 64)  binS[tid] = b_in[tid];

  // ---- gate weight fragments (96 VGPR) + scalar bias ----
  short8 fb[4][6];
  float  bias[4];
  #pragma unroll
  for (int g = 0; g < 4; ++g) {
    const int grow = g * 128 + u;
    bias[g] = b_ih[grow] + b_hh[grow];
    #pragma unroll
    for (int kt = 0; kt < 6; ++kt) {
      const int kk = kt * 32 + lq * 8;
      const float* src = (kk < 64) ? (W_ih + grow * 64 + kk)
                                   : (W_hh + grow * 128 + (kk - 64));
      fb[g][kt] = packbf8(src);
    }
  }
  // y-proj fragments -> LDS (wave 0 loads)
  if (w == 0) {
    #pragma unroll
    for (int kt = 0; kt < 4; ++kt) {
      short8 fy = {0, 0, 0, 0, 0, 0, 0, 0};
      if (l15 < 2) fy = packbf8(W_out + l15 * 128 + kt * 32 + lq * 8);
      *(short8*)&fyB[(kt * 64 + l) * 8] = fy;
    }
  }
  const float bout_r = (l15 < 2) ? b_out[l15] : 0.f;

  __syncthreads();   // xsT, WinS, binS, fyB ready

  // ---- zero pad rows 8-15 of both buffers (full ASTR) ----
  for (int j = tid; j < 1600; j += 512) {
    const int buf = j / 800, rem = j % 800;
    const int r = 8 + rem / 100, c = (rem % 100) * 2;
    *(unsigned*)&Abuf[buf][r][c] = 0u;
  }
  // zero h-region rows 0-7 of buf0 (512 u32)
  {
    const int r = tid >> 6;
    ((unsigned*)&Abuf[0][r][64])[tid & 63] = 0u;
  }
  // embed e0 -> buf0 (1 value/thread: wave w handles row w)
  {
    const int r = w, e = l;
    const float x0 = xsT[0][r], x1 = xsT[1][r];
    float v = fmaf(x1, WinS[2 * e + 1], fmaf(x0, WinS[2 * e], binS[e]));
    Abuf[0][r][e] = f2bf(v > 0.f ? v : 0.f);
  }
  __syncthreads();

  f32x2 c01 = {0.f, 0.f}, c23 = {0.f, 0.f};
  const size_t obase = (size_t)blockIdx.x * (8 * 2 * T_LEN);
  const int yrow = (lq & 1) * 4;   // row base for y residual reads

  for (int t = 0; t < T_LEN; ++t) {
    const int p = t & 1;
    const unsigned short (*bR)[ASTR] = Abuf[p];
    unsigned short (*bW)[ASTR] = Abuf[p ^ 1];

    // A fragments (6 k-tiles)
    short8 a0 = *(const short8*)&bR[l15][0 * 32 + lq * 8];
    short8 a1 = *(const short8*)&bR[l15][1 * 32 + lq * 8];
    short8 a2 = *(const short8*)&bR[l15][2 * 32 + lq * 8];
    short8 a3 = *(const short8*)&bR[l15][3 * 32 + lq * 8];
    short8 a4 = *(const short8*)&bR[l15][4 * 32 + lq * 8];
    short8 a5 = *(const short8*)&bR[l15][5 * 32 + lq * 8];

    f32x4 acc[4];
    #pragma unroll
    for (int g = 0; g < 4; ++g) {
      f32x4 s = (f32x4){bias[g], bias[g], bias[g], bias[g]};
      s = MFMA(a0, fb[g][0], s, 0, 0, 0);
      s = MFMA(a1, fb[g][1], s, 0, 0, 0);
      s = MFMA(a2, fb[g][2], s, 0, 0, 0);
      s = MFMA(a3, fb[g][3], s, 0, 0, 0);
      s = MFMA(a4, fb[g][4], s, 0, 0, 0);
      s = MFMA(a5, fb[g][5], s, 0, 0, 0);
      acc[g] = s;
    }

    // y_{t-1} = h_t @ W_out^T + b_out + x_{t-1}  (wave 0; h_t = a2..a5)
    if (w == 0) {
      const int tt = t ? t - 1 : 0;
      f32x4 accY;
      #pragma unroll
      for (int q = 0; q < 4; ++q)
        accY[q] = (l15 < 2) ? (bout_r + xsT[2 * tt + l15][yrow + q]) : 0.f;
      const short8 fy0 = *(const short8*)&fyB[(0 * 64 + l) * 8];
      const short8 fy1 = *(const short8*)&fyB[(1 * 64 + l) * 8];
      const short8 fy2 = *(const short8*)&fyB[(2 * 64 + l) * 8];
      const short8 fy3 = *(const short8*)&fyB[(3 * 64 + l) * 8];
      accY = MFMA(a2, fy0, accY, 0, 0, 0);
      accY = MFMA(a3, fy1, accY, 0, 0, 0);
      accY = MFMA(a4, fy2, accY, 0, 0, 0);
      accY = MFMA(a5, fy3, accY, 0, 0, 0);
      if (t > 0 && l15 < 2 && lq < 2) {
        #pragma unroll
        for (int q = 0; q < 4; ++q)
          out[obase + (size_t)(lq * 4 + q) * (2 * T_LEN) + 2 * (t - 1) + l15] = accY[q];
      }
    }

    // EW (rows 0-7 live on lq<2) -> h_{t+1} into bW
    if (lq < 2) {
      const int row0 = lq * 4;
      {
        f32x2 iv = {acc[0][0], acc[0][1]}, fv = {acc[1][0], acc[1][1]};
        f32x2 gv = {acc[2][0], acc[2][1]}, ov = {acc[3][0], acc[3][1]};
        f32x2 h01 = ewpair(iv, fv, gv, ov, c01);
        bW[row0 + 0][64 + u] = f2bf(h01[0]);
        bW[row0 + 1][64 + u] = f2bf(h01[1]);
      }
      {
        f32x2 iv = {acc[0][2], acc[0][3]}, fv = {acc[1][2], acc[1][3]};
        f32x2 gv = {acc[2][2], acc[2][3]}, ov = {acc[3][2], acc[3][3]};
        f32x2 h23 = ewpair(iv, fv, gv, ov, c23);
        bW[row0 + 2][64 + u] = f2bf(h23[0]);
        bW[row0 + 3][64 + u] = f2bf(h23[1]);
      }
    }

    // embed e_{t+1} -> bW (1 value/thread)
    if (t + 1 < T_LEN) {
      const int r = w, e = l;
      const float x0 = xsT[2 * (t + 1)][r], x1 = xsT[2 * (t + 1) + 1][r];
      float v = fmaf(x1, WinS[2 * e + 1], fmaf(x0, WinS[2 * e], binS[e]));
      bW[r][e] = f2bf(v > 0.f ? v : 0.f);
    }

    __syncthreads();   // ONE barrier per step
  }

  // epilogue: y_255 = h_256 @ W_out^T + b_out + x_255 ; h_256 is in Abuf[0]
  if (w == 0) {
    const unsigned short (*hb)[ASTR] = Abuf[0];
    const short8 a2 = *(const short8*)&hb[l15][2 * 32 + lq * 8];
    const short8 a3 = *(const short8*)&hb[l15][3 * 32 + lq * 8];
    const short8 a4 = *(const short8*)&hb[l15][4 * 32 + lq * 8];
    const short8 a5 = *(const short8*)&hb[l15][5 * 32 + lq * 8];
    f32x4 accY;
    #pragma unroll
    for (int q = 0; q < 4; ++q)
      accY[q] = (l15 < 2) ? (bout_r + xsT[2 * 255 + l15][yrow + q]) : 0.f;
    const short8 fy0 = *(const short8*)&fyB[(0 * 64 + l) * 8];
    const short8 fy1 = *(const short8*)&fyB[(1 * 64 + l) * 8];
    const short8 fy2 = *(const short8*)&fyB[(2 * 64 + l) * 8];
    const short8 fy3 = *(const short8*)&fyB[(3 * 64 + l) * 8];
    accY = MFMA(a2, fy0, accY, 0, 0, 0);
    accY = MFMA(a3, fy1, accY, 0, 0, 0);
    accY = MFMA(a4, fy2, accY, 0, 0, 0);
    accY = MFMA(a5, fy3, accY, 0, 0, 0);
    if (l15 < 2 && lq < 2) {
      #pragma unroll
      for (int q = 0; q < 4; ++q)
        out[obase + (size_t)(lq * 4 + q) * (2 * T_LEN) + 2 * 255 + l15] = accY[q];
    }
  }
}

extern "C" void kernel_launch(void* const* d_in, const int* in_sizes, int n_in,
                              void* d_out, int out_size, void* d_ws, size_t ws_size,
                              hipStream_t stream) {
  const float* x     = (const float*)d_in[0];
  const float* W_in  = (const float*)d_in[1];
  const float* b_in  = (const float*)d_in[2];
  const float* W_ih  = (const float*)d_in[3];
  const float* W_hh  = (const float*)d_in[4];
  const float* b_ih  = (const float*)d_in[5];
  const float* b_hh  = (const float*)d_in[6];
  const float* W_out = (const float*)d_in[7];
  const float* b_out = (const float*)d_in[8];
  float* out = (float*)d_out;

  lstm_persist<<<dim3(512), dim3(512), 0, stream>>>(
      x, W_in, b_in, W_ih, W_hh, b_ih, b_hh, W_out, b_out, out);
}

// Round 7
// 311.522 us; speedup vs baseline: 5.5420x; 1.7260x over previous
//
#include <hip/hip_runtime.h>

// Persistent LSTM: N=4096, T=256, IN=2, E=64, H=128, OUT=2.
// 256 blocks x 1024 threads (16 waves), block b owns rows [16b,16b+16).
// HETEROGENEOUS SPLIT at the embed seam (no per-cell exchange, 1 barrier/step):
//  - waves 0-7 ("unit"): W_hh frags only (4 gates x 4 kt = 64 VGPR). Per step:
//    acc init <- gates_x[t] (fp32 LDS), 4 h-frag reads, 16 MFMAs, register-local
//    EW (4 cells/lane), h_{t+1} -> swizzled LDS.
//  - waves 8-15 ("spare"): W_ih frags (32 VGPR). Per step: produce
//    gates_x[t+1] = embed_{t+1} @ W_ih^T + (b_ih+b_hh) via 8 MFMAs into the
//    ping-pong gx buffer; embed scalars for t+2; wave 8 also does the lag-1
//    y-projection (4 MFMAs, fy frags from LDS) -- off the unit critical path.
// __launch_bounds__(1024, 1): HIP 2nd arg ~ min BLOCKS/CU (r5/r6 evidence:
// (512,4)->cap64+spills, (512,2)->128, (1024,4)->cap64+76MB spill traffic).
// 1 block/CU, 16 waves = 4/SIMD, VGPR cap 128 -> no spills (unit path ~120).

#define T_LEN 256

typedef __attribute__((ext_vector_type(8))) short short8;
typedef __attribute__((ext_vector_type(4))) float f32x4;
typedef __attribute__((ext_vector_type(2))) float f32x2;

__device__ __forceinline__ unsigned short f2bf(float f) {
  unsigned u = __builtin_bit_cast(unsigned, f);
  u += 0x7fffu + ((u >> 16) & 1u);           // RNE
  return (unsigned short)(u >> 16);
}
__device__ __forceinline__ f32x2 exp2v(f32x2 x) {
  return (f32x2){__builtin_amdgcn_exp2f(x[0]), __builtin_amdgcn_exp2f(x[1])};
}
__device__ __forceinline__ f32x2 rcpv(f32x2 x) {
  return (f32x2){__builtin_amdgcn_rcpf(x[0]), __builtin_amdgcn_rcpf(x[1])};
}

// fused LSTM cell on 2 rows: sig(x)=1/(1+2^(K1 x)), tanh=(1-2^(K2 x))/(1+2^(K2 x))
__device__ __forceinline__ f32x2 ewpair(f32x2 i, f32x2 f, f32x2 g, f32x2 o, f32x2& c) {
  const float K1 = -1.4426950408889634f, K2 = -2.8853900817779268f;
  f32x2 ei = exp2v(i * K1);
  f32x2 ef = exp2v(f * K1);
  f32x2 eg = exp2v(g * K2);
  f32x2 eo = exp2v(o * K1);
  f32x2 t1 = ei + 1.f, tf = ef + 1.f, t2 = eg + 1.f, t3 = 1.f - eg, to = eo + 1.f;
  f32x2 q1 = t1 * t2;
  f32x2 num = c * q1 + t3 * tf;
  f32x2 cn = num * rcpv(q1 * tf);
  c = cn;
  f32x2 cc = __builtin_elementwise_min(
      __builtin_elementwise_max(cn, (f32x2){-20.f, -20.f}), (f32x2){20.f, 20.f});
  f32x2 ec = exp2v(cc * K2);
  return (1.f - ec) * rcpv(to * (ec + 1.f));
}

__device__ __forceinline__ short8 packbf8(const float* src) {
  float4 lo = *(const float4*)src;
  float4 hi = *(const float4*)(src + 4);
  short8 f;
  f[0] = (short)f2bf(lo.x); f[1] = (short)f2bf(lo.y);
  f[2] = (short)f2bf(lo.z); f[3] = (short)f2bf(lo.w);
  f[4] = (short)f2bf(hi.x); f[5] = (short)f2bf(hi.y);
  f[6] = (short)f2bf(hi.z); f[7] = (short)f2bf(hi.w);
  return f;
}

#define MFMA __builtin_amdgcn_mfma_f32_16x16x32_bf16

__global__ __launch_bounds__(1024, 1) void lstm_persist(
    const float* __restrict__ x,    const float* __restrict__ W_in,
    const float* __restrict__ b_in, const float* __restrict__ W_ih,
    const float* __restrict__ W_hh, const float* __restrict__ b_ih,
    const float* __restrict__ b_hh, const float* __restrict__ W_out,
    const float* __restrict__ b_out, float* __restrict__ out)
{
  __shared__ __align__(16) float xsT[2 * T_LEN][16];           // 32 KB
  __shared__ float WinS[128];
  __shared__ float binS[64];
  __shared__ __align__(16) unsigned short embB[2][16 * 64];    // 4 KB  (swizzled)
  __shared__ __align__(16) unsigned short hB[2][16 * 128];     // 8 KB  (swizzled)
  __shared__ __align__(16) float gx[2][512 * 20];              // 80 KB (80B col stride)
  __shared__ __align__(16) unsigned short fyB[4 * 64 * 8];     // 4 KB  y-proj B frags

  const int tid = threadIdx.x;
  const int w   = tid >> 6;
  const int l   = tid & 63;
  const int l15 = l & 15;
  const int lq  = l >> 4;
  const int w8  = w & 7;
  const bool is_unit = (w < 8);

  // ---- stage x transposed ----
  const float* xg = x + (size_t)blockIdx.x * (16 * 2 * T_LEN);
  #pragma unroll
  for (int i = tid; i < 2048; i += 1024) {
    float4 v = ((const float4*)xg)[i];
    int fi = i * 4, r = fi >> 9, c0 = fi & 511;
    xsT[c0][r] = v.x; xsT[c0 + 1][r] = v.y; xsT[c0 + 2][r] = v.z; xsT[c0 + 3][r] = v.w;
  }
  if (tid < 128) WinS[tid] = W_in[tid];
  if (tid < 64)  binS[tid] = b_in[tid];

  // ---- per-role weight fragments (FB shared: unit uses [0..15], spare [0..7]) ----
  short8 FB[16];
  float  biasC[4];
  float  bout_r = 0.f;
  if (is_unit) {
    #pragma unroll
    for (int g = 0; g < 4; ++g) {
      const int grow = g * 128 + 16 * w8 + l15;
      #pragma unroll
      for (int kt = 0; kt < 4; ++kt)
        FB[g * 4 + kt] = packbf8(W_hh + grow * 128 + kt * 32 + lq * 8);
    }
  } else {
    #pragma unroll
    for (int tt = 0; tt < 4; ++tt) {
      const int col = 64 * w8 + 16 * tt + l15;     // col == gate*128+unit
      biasC[tt] = b_ih[col] + b_hh[col];
      #pragma unroll
      for (int kt = 0; kt < 2; ++kt)
        FB[tt * 2 + kt] = packbf8(W_ih + col * 64 + kt * 32 + lq * 8);
    }
    bout_r = (l15 < 2) ? b_out[l15] : 0.f;
    if (w == 8) {
      #pragma unroll
      for (int kt = 0; kt < 4; ++kt) {
        short8 fy = {0, 0, 0, 0, 0, 0, 0, 0};
        if (l15 < 2) fy = packbf8(W_out + l15 * 128 + kt * 32 + lq * 8);
        *(short8*)&fyB[(kt * 64 + l) * 8] = fy;
      }
    }
  }
  __syncthreads();   // xsT, WinS, binS, fyB ready

  // ---- emb scalars for t=0,1 ; zero hB[0] ----
  {
    const int tt = tid >> 9;            // 0 or 1
    const int s  = tid & 511;
    const int r = s >> 5, e0 = (s & 31) * 2;
    const float x0 = xsT[2 * tt][r], x1 = xsT[2 * tt + 1][r];
    float v0 = fmaf(x1, WinS[2 * e0 + 1], fmaf(x0, WinS[2 * e0], binS[e0]));
    float v1 = fmaf(x1, WinS[2 * e0 + 3], fmaf(x0, WinS[2 * e0 + 2], binS[e0 + 1]));
    v0 = v0 > 0.f ? v0 : 0.f; v1 = v1 > 0.f ? v1 : 0.f;
    const int ei = r * 64 + (((e0 >> 3) ^ (r & 7)) * 8) + (e0 & 7);
    *(unsigned*)&embB[tt][ei] = (unsigned)f2bf(v0) | ((unsigned)f2bf(v1) << 16);
    ((unsigned*)&hB[0][0])[tid] = 0u;
  }
  __syncthreads();   // embB[0], embB[1], hB[0]

  // ---- spares: gx[0] from embB[0] ----
  if (!is_unit) {
    const short8 ae0 = *(const short8*)&embB[0][l15 * 64 + ((lq ^ (l15 & 7)) * 8)];
    const short8 ae1 = *(const short8*)&embB[0][l15 * 64 + (((4 + lq) ^ (l15 & 7)) * 8)];
    #pragma unroll
    for (int tt = 0; tt < 4; ++tt) {
      f32x4 a = (f32x4){biasC[tt], biasC[tt], biasC[tt], biasC[tt]};
      a = MFMA(ae0, FB[tt * 2 + 0], a, 0, 0, 0);
      a = MFMA(ae1, FB[tt * 2 + 1], a, 0, 0, 0);
      *(f32x4*)&gx[0][(64 * w8 + 16 * tt + l15) * 20 + lq * 4] = a;
    }
  }
  __syncthreads();   // gx[0]

  f32x2 c01 = {0.f, 0.f}, c23 = {0.f, 0.f};
  const size_t obase = (size_t)blockIdx.x * (16 * 2 * T_LEN);
  const int u = 16 * w8 + l15;
  int hw[4];
  #pragma unroll
  for (int q = 0; q < 4; ++q) {
    const int r = lq * 4 + q;
    hw[q] = r * 128 + (((u >> 3) ^ (r & 7)) * 8) + (u & 7);
  }

  for (int t = 0; t < T_LEN; ++t) {
    const int p = t & 1;
    if (is_unit) {
      // acc init <- gates_x[t]
      const float* gxp = &gx[p][(16 * w8 + l15) * 20 + lq * 4];
      f32x4 acc0 = *(const f32x4*)(gxp + 0 * 2560);
      f32x4 acc1 = *(const f32x4*)(gxp + 1 * 2560);
      f32x4 acc2 = *(const f32x4*)(gxp + 2 * 2560);
      f32x4 acc3 = *(const f32x4*)(gxp + 3 * 2560);
      // h fragments
      const unsigned short* hb = hB[p];
      const short8 ah0 = *(const short8*)&hb[l15 * 128 + (((0 * 4 + lq) ^ (l15 & 7)) * 8)];
      const short8 ah1 = *(const short8*)&hb[l15 * 128 + (((1 * 4 + lq) ^ (l15 & 7)) * 8)];
      const short8 ah2 = *(const short8*)&hb[l15 * 128 + (((2 * 4 + lq) ^ (l15 & 7)) * 8)];
      const short8 ah3 = *(const short8*)&hb[l15 * 128 + (((3 * 4 + lq) ^ (l15 & 7)) * 8)];
      acc0 = MFMA(ah0, FB[0],  acc0, 0, 0, 0);
      acc1 = MFMA(ah0, FB[4],  acc1, 0, 0, 0);
      acc2 = MFMA(ah0, FB[8],  acc2, 0, 0, 0);
      acc3 = MFMA(ah0, FB[12], acc3, 0, 0, 0);
      acc0 = MFMA(ah1, FB[1],  acc0, 0, 0, 0);
      acc1 = MFMA(ah1, FB[5],  acc1, 0, 0, 0);
      acc2 = MFMA(ah1, FB[9],  acc2, 0, 0, 0);
      acc3 = MFMA(ah1, FB[13], acc3, 0, 0, 0);
      acc0 = MFMA(ah2, FB[2],  acc0, 0, 0, 0);
      acc1 = MFMA(ah2, FB[6],  acc1, 0, 0, 0);
      acc2 = MFMA(ah2, FB[10], acc2, 0, 0, 0);
      acc3 = MFMA(ah2, FB[14], acc3, 0, 0, 0);
      acc0 = MFMA(ah3, FB[3],  acc0, 0, 0, 0);
      acc1 = MFMA(ah3, FB[7],  acc1, 0, 0, 0);
      acc2 = MFMA(ah3, FB[11], acc2, 0, 0, 0);
      acc3 = MFMA(ah3, FB[15], acc3, 0, 0, 0);

      // EW (register-local, 4 cells) -> h_{t+1}
      unsigned short* hbW = hB[p ^ 1];
      {
        f32x2 iv = {acc0[0], acc0[1]}, fv = {acc1[0], acc1[1]};
        f32x2 gv = {acc2[0], acc2[1]}, ov = {acc3[0], acc3[1]};
        f32x2 h01 = ewpair(iv, fv, gv, ov, c01);
        hbW[hw[0]] = f2bf(h01[0]);
        hbW[hw[1]] = f2bf(h01[1]);
      }
      {
        f32x2 iv = {acc0[2], acc0[3]}, fv = {acc1[2], acc1[3]};
        f32x2 gv = {acc2[2], acc2[3]}, ov = {acc3[2], acc3[3]};
        f32x2 h23 = ewpair(iv, fv, gv, ov, c23);
        hbW[hw[2]] = f2bf(h23[0]);
        hbW[hw[3]] = f2bf(h23[1]);
      }
    } else {
      // spare wave 8: y_{t-1} = h_t @ W_out^T + b_out + x_{t-1}
      if (w == 8) {
        const unsigned short* hb = hB[p];
        const short8 ah0 = *(const short8*)&hb[l15 * 128 + (((0 * 4 + lq) ^ (l15 & 7)) * 8)];
        const short8 ah1 = *(const short8*)&hb[l15 * 128 + (((1 * 4 + lq) ^ (l15 & 7)) * 8)];
        const short8 ah2 = *(const short8*)&hb[l15 * 128 + (((2 * 4 + lq) ^ (l15 & 7)) * 8)];
        const short8 ah3 = *(const short8*)&hb[l15 * 128 + (((3 * 4 + lq) ^ (l15 & 7)) * 8)];
        const int ttm = t ? t - 1 : 0;
        f32x4 accY;
        #pragma unroll
        for (int q = 0; q < 4; ++q)
          accY[q] = (l15 < 2) ? (bout_r + xsT[2 * ttm + l15][lq * 4 + q]) : 0.f;
        const short8 fy0 = *(const short8*)&fyB[(0 * 64 + l) * 8];
        const short8 fy1 = *(const short8*)&fyB[(1 * 64 + l) * 8];
        const short8 fy2 = *(const short8*)&fyB[(2 * 64 + l) * 8];
        const short8 fy3 = *(const short8*)&fyB[(3 * 64 + l) * 8];
        accY = MFMA(ah0, fy0, accY, 0, 0, 0);
        accY = MFMA(ah1, fy1, accY, 0, 0, 0);
        accY = MFMA(ah2, fy2, accY, 0, 0, 0);
        accY = MFMA(ah3, fy3, accY, 0, 0, 0);
        if (t > 0 && l15 < 2) {
          #pragma unroll
          for (int q = 0; q < 4; ++q)
            out[obase + (size_t)(lq * 4 + q) * (2 * T_LEN) + 2 * (t - 1) + l15] = accY[q];
        }
      }
      // spares: gates_x[t+1] = embed_{t+1} @ W_ih^T + bias
      if (t < T_LEN - 1) {
        const int pn = (t + 1) & 1;
        const unsigned short* eb = embB[pn];
        const short8 ae0 = *(const short8*)&eb[l15 * 64 + ((lq ^ (l15 & 7)) * 8)];
        const short8 ae1 = *(const short8*)&eb[l15 * 64 + (((4 + lq) ^ (l15 & 7)) * 8)];
        #pragma unroll
        for (int tt = 0; tt < 4; ++tt) {
          f32x4 a = (f32x4){biasC[tt], biasC[tt], biasC[tt], biasC[tt]};
          a = MFMA(ae0, FB[tt * 2 + 0], a, 0, 0, 0);
          a = MFMA(ae1, FB[tt * 2 + 1], a, 0, 0, 0);
          *(f32x4*)&gx[pn][(64 * w8 + 16 * tt + l15) * 20 + lq * 4] = a;
        }
      }
      // embed scalars for t+2
      if (t < T_LEN - 2) {
        const int s = w8 * 64 + l;
        const int r = s >> 5, e0 = (s & 31) * 2;
        const int te = t + 2;
        const float x0 = xsT[2 * te][r], x1 = xsT[2 * te + 1][r];
        float v0 = fmaf(x1, WinS[2 * e0 + 1], fmaf(x0, WinS[2 * e0], binS[e0]));
        float v1 = fmaf(x1, WinS[2 * e0 + 3], fmaf(x0, WinS[2 * e0 + 2], binS[e0 + 1]));
        v0 = v0 > 0.f ? v0 : 0.f; v1 = v1 > 0.f ? v1 : 0.f;
        const int ei = r * 64 + (((e0 >> 3) ^ (r & 7)) * 8) + (e0 & 7);
        *(unsigned*)&embB[t & 1][ei] = (unsigned)f2bf(v0) | ((unsigned)f2bf(v1) << 16);
      }
    }
    __syncthreads();   // the ONE barrier per step
  }

  // epilogue: y_255 = h_256 @ W_out^T + b_out + x_255 ; h_256 is in hB[0]
  if (w == 8) {
    const unsigned short* hb = hB[0];
    const short8 ah0 = *(const short8*)&hb[l15 * 128 + (((0 * 4 + lq) ^ (l15 & 7)) * 8)];
    const short8 ah1 = *(const short8*)&hb[l15 * 128 + (((1 * 4 + lq) ^ (l15 & 7)) * 8)];
    const short8 ah2 = *(const short8*)&hb[l15 * 128 + (((2 * 4 + lq) ^ (l15 & 7)) * 8)];
    const short8 ah3 = *(const short8*)&hb[l15 * 128 + (((3 * 4 + lq) ^ (l15 & 7)) * 8)];
    f32x4 accY;
    #pragma unroll
    for (int q = 0; q < 4; ++q)
      accY[q] = (l15 < 2) ? (bout_r + xsT[2 * 255 + l15][lq * 4 + q]) : 0.f;
    const short8 fy0 = *(const short8*)&fyB[(0 * 64 + l) * 8];
    const short8 fy1 = *(const short8*)&fyB[(1 * 64 + l) * 8];
    const short8 fy2 = *(const short8*)&fyB[(2 * 64 + l) * 8];
    const short8 fy3 = *(const short8*)&fyB[(3 * 64 + l) * 8];
    accY = MFMA(ah0, fy0, accY, 0, 0, 0);
    accY = MFMA(ah1, fy1, accY, 0, 0, 0);
    accY = MFMA(ah2, fy2, accY, 0, 0, 0);
    accY = MFMA(ah3, fy3, accY, 0, 0, 0);
    if (l15 < 2) {
      #pragma unroll
      for (int q = 0; q < 4; ++q)
        out[obase + (size_t)(lq * 4 + q) * (2 * T_LEN) + 2 * 255 + l15] = accY[q];
    }
  }
}

extern "C" void kernel_launch(void* const* d_in, const int* in_sizes, int n_in,
                              void* d_out, int out_size, void* d_ws, size_t ws_size,
                              hipStream_t stream) {
  const float* x     = (const float*)d_in[0];
  const float* W_in  = (const float*)d_in[1];
  const float* b_in  = (const float*)d_in[2];
  const float* W_ih  = (const float*)d_in[3];
  const float* W_hh  = (const float*)d_in[4];
  const float* b_ih  = (const float*)d_in[5];
  const float* b_hh  = (const float*)d_in[6];
  const float* W_out = (const float*)d_in[7];
  const float* b_out = (const float*)d_in[8];
  float* out = (float*)d_out;

  lstm_persist<<<dim3(256), dim3(1024), 0, stream>>>(
      x, W_in, b_in, W_ih, W_hh, b_ih, b_hh, W_out, b_out, out);
}

// Round 8
// 303.673 us; speedup vs baseline: 5.6853x; 1.0258x over previous
//
#include <hip/hip_runtime.h>

// Persistent LSTM: N=4096, T=256, IN=2, E=64, H=128, OUT=2.
// 256 blocks x 768 threads (12 waves = exactly 3 waves/SIMD), block b owns
// rows [16b,16b+16). Heterogeneous split at the embed seam, 1 barrier/step:
//  - waves 0-7 ("unit"): W_hh frags (64 VGPR). Per step: acc init <- gates_x[t]
//    (fp32 LDS), 4 h-frag reads, 16 MFMAs, register-local EW (4 cells/lane),
//    h_{t+1} -> swizzled LDS.
//  - waves 8-11 ("spare"): wave 8+w4 owns gate w4's 128 cols. Per step:
//    gates_x[t+1] = embed_{t+1} @ W_ih^T + bias (16 MFMAs) -> ping-pong gx;
//    embed scalars for t+2 (2/lane); wave 8 also does lag-1 y-projection.
// REGISTER PINNING (r5-r7 evidence: 512-VGPR/SIMD pool incl AGPR; compiler
// heuristic targets 8 waves/SIMD for 1024-thr blocks -> cap 64 -> hot-loop
// spills, 18MB scratch traffic): amdgpu_waves_per_eu(3,3) pins budget to
// ~170/wave so the ~150-reg unit path fits spill-free.

#define T_LEN 256

typedef __attribute__((ext_vector_type(8))) short short8;
typedef __attribute__((ext_vector_type(4))) float f32x4;
typedef __attribute__((ext_vector_type(2))) float f32x2;

__device__ __forceinline__ unsigned short f2bf(float f) {
  unsigned u = __builtin_bit_cast(unsigned, f);
  u += 0x7fffu + ((u >> 16) & 1u);           // RNE
  return (unsigned short)(u >> 16);
}
__device__ __forceinline__ f32x2 exp2v(f32x2 x) {
  return (f32x2){__builtin_amdgcn_exp2f(x[0]), __builtin_amdgcn_exp2f(x[1])};
}
__device__ __forceinline__ f32x2 rcpv(f32x2 x) {
  return (f32x2){__builtin_amdgcn_rcpf(x[0]), __builtin_amdgcn_rcpf(x[1])};
}

// fused LSTM cell on 2 rows: sig(x)=1/(1+2^(K1 x)), tanh=(1-2^(K2 x))/(1+2^(K2 x))
__device__ __forceinline__ f32x2 ewpair(f32x2 i, f32x2 f, f32x2 g, f32x2 o, f32x2& c) {
  const float K1 = -1.4426950408889634f, K2 = -2.8853900817779268f;
  f32x2 ei = exp2v(i * K1);
  f32x2 ef = exp2v(f * K1);
  f32x2 eg = exp2v(g * K2);
  f32x2 eo = exp2v(o * K1);
  f32x2 t1 = ei + 1.f, tf = ef + 1.f, t2 = eg + 1.f, t3 = 1.f - eg, to = eo + 1.f;
  f32x2 q1 = t1 * t2;
  f32x2 num = c * q1 + t3 * tf;
  f32x2 cn = num * rcpv(q1 * tf);
  c = cn;
  f32x2 cc = __builtin_elementwise_min(
      __builtin_elementwise_max(cn, (f32x2){-20.f, -20.f}), (f32x2){20.f, 20.f});
  f32x2 ec = exp2v(cc * K2);
  return (1.f - ec) * rcpv(to * (ec + 1.f));
}

__device__ __forceinline__ short8 packbf8(const float* src) {
  float4 lo = *(const float4*)src;
  float4 hi = *(const float4*)(src + 4);
  short8 f;
  f[0] = (short)f2bf(lo.x); f[1] = (short)f2bf(lo.y);
  f[2] = (short)f2bf(lo.z); f[3] = (short)f2bf(lo.w);
  f[4] = (short)f2bf(hi.x); f[5] = (short)f2bf(hi.y);
  f[6] = (short)f2bf(hi.z); f[7] = (short)f2bf(hi.w);
  return f;
}

#define MFMA __builtin_amdgcn_mfma_f32_16x16x32_bf16

__global__ void __attribute__((amdgpu_flat_work_group_size(768, 768),
                               amdgpu_waves_per_eu(3, 3)))
lstm_persist(
    const float* __restrict__ x,    const float* __restrict__ W_in,
    const float* __restrict__ b_in, const float* __restrict__ W_ih,
    const float* __restrict__ W_hh, const float* __restrict__ b_ih,
    const float* __restrict__ b_hh, const float* __restrict__ W_out,
    const float* __restrict__ b_out, float* __restrict__ out)
{
  __shared__ __align__(16) float xsT[2 * T_LEN][16];           // 32 KB
  __shared__ float WinS[128];
  __shared__ float binS[64];
  __shared__ __align__(16) unsigned short embB[2][16 * 64];    // 4 KB  (swizzled)
  __shared__ __align__(16) unsigned short hB[2][16 * 128];     // 8 KB  (swizzled)
  __shared__ __align__(16) float gx[2][512 * 20];              // 80 KB (80B col stride)
  __shared__ __align__(16) unsigned short fyB[4 * 64 * 8];     // 4 KB  y-proj B frags

  const int tid = threadIdx.x;
  const int w   = tid >> 6;        // 0..11
  const int l   = tid & 63;
  const int l15 = l & 15;
  const int lq  = l >> 4;
  const int w8  = w & 7;           // unit-wave id
  const int w4  = w - 8;           // spare-wave id (gate), valid when w>=8
  const bool is_unit = (w < 8);

  // ---- stage x transposed ----
  const float* xg = x + (size_t)blockIdx.x * (16 * 2 * T_LEN);
  for (int i = tid; i < 2048; i += 768) {
    float4 v = ((const float4*)xg)[i];
    int fi = i * 4, r = fi >> 9, c0 = fi & 511;
    xsT[c0][r] = v.x; xsT[c0 + 1][r] = v.y; xsT[c0 + 2][r] = v.z; xsT[c0 + 3][r] = v.w;
  }
  if (tid < 128) WinS[tid] = W_in[tid];
  if (tid < 64)  binS[tid] = b_in[tid];

  // ---- per-role weight fragments ----
  short8 FB[16];
  float  biasC[8];
  float  bout_r = 0.f;
  if (is_unit) {
    #pragma unroll
    for (int g = 0; g < 4; ++g) {
      const int grow = g * 128 + 16 * w8 + l15;
      #pragma unroll
      for (int kt = 0; kt < 4; ++kt)
        FB[g * 4 + kt] = packbf8(W_hh + grow * 128 + kt * 32 + lq * 8);
    }
  } else {
    #pragma unroll
    for (int tt = 0; tt < 8; ++tt) {
      const int col = 128 * w4 + 16 * tt + l15;    // col == gate*128+unit
      biasC[tt] = b_ih[col] + b_hh[col];
      #pragma unroll
      for (int kt = 0; kt < 2; ++kt)
        FB[tt * 2 + kt] = packbf8(W_ih + col * 64 + kt * 32 + lq * 8);
    }
    bout_r = (l15 < 2) ? b_out[l15] : 0.f;
    if (w == 8) {
      #pragma unroll
      for (int kt = 0; kt < 4; ++kt) {
        short8 fy = {0, 0, 0, 0, 0, 0, 0, 0};
        if (l15 < 2) fy = packbf8(W_out + l15 * 128 + kt * 32 + lq * 8);
        *(short8*)&fyB[(kt * 64 + l) * 8] = fy;
      }
    }
  }
  __syncthreads();   // xsT, WinS, binS, fyB ready

  // ---- emb scalars for t=0,1 ; zero hB[0] ----
  for (int i = tid; i < 1024; i += 768) {
    const int tt = i >> 9;            // 0 or 1
    const int s  = i & 511;
    const int r = s >> 5, e0 = (s & 31) * 2;
    const float x0 = xsT[2 * tt][r], x1 = xsT[2 * tt + 1][r];
    float v0 = fmaf(x1, WinS[2 * e0 + 1], fmaf(x0, WinS[2 * e0], binS[e0]));
    float v1 = fmaf(x1, WinS[2 * e0 + 3], fmaf(x0, WinS[2 * e0 + 2], binS[e0 + 1]));
    v0 = v0 > 0.f ? v0 : 0.f; v1 = v1 > 0.f ? v1 : 0.f;
    const int ei = r * 64 + (((e0 >> 3) ^ (r & 7)) * 8) + (e0 & 7);
    *(unsigned*)&embB[tt][ei] = (unsigned)f2bf(v0) | ((unsigned)f2bf(v1) << 16);
  }
  for (int i = tid; i < 1024; i += 768)
    ((unsigned*)&hB[0][0])[i] = 0u;
  __syncthreads();   // embB[0], embB[1], hB[0]

  // ---- spares: gx[0] from embB[0] ----
  if (!is_unit) {
    const short8 ae0 = *(const short8*)&embB[0][l15 * 64 + ((lq ^ (l15 & 7)) * 8)];
    const short8 ae1 = *(const short8*)&embB[0][l15 * 64 + (((4 + lq) ^ (l15 & 7)) * 8)];
    #pragma unroll
    for (int tt = 0; tt < 8; ++tt) {
      f32x4 a = (f32x4){biasC[tt], biasC[tt], biasC[tt], biasC[tt]};
      a = MFMA(ae0, FB[tt * 2 + 0], a, 0, 0, 0);
      a = MFMA(ae1, FB[tt * 2 + 1], a, 0, 0, 0);
      *(f32x4*)&gx[0][(128 * w4 + 16 * tt + l15) * 20 + lq * 4] = a;
    }
  }
  __syncthreads();   // gx[0]

  f32x2 c01 = {0.f, 0.f}, c23 = {0.f, 0.f};
  const size_t obase = (size_t)blockIdx.x * (16 * 2 * T_LEN);
  const int u = 16 * w8 + l15;
  int hw[4];
  #pragma unroll
  for (int q = 0; q < 4; ++q) {
    const int r = lq * 4 + q;
    hw[q] = r * 128 + (((u >> 3) ^ (r & 7)) * 8) + (u & 7);
  }

  for (int t = 0; t < T_LEN; ++t) {
    const int p = t & 1;
    if (is_unit) {
      // acc init <- gates_x[t]
      const float* gxp = &gx[p][(16 * w8 + l15) * 20 + lq * 4];
      f32x4 acc0 = *(const f32x4*)(gxp + 0 * 2560);
      f32x4 acc1 = *(const f32x4*)(gxp + 1 * 2560);
      f32x4 acc2 = *(const f32x4*)(gxp + 2 * 2560);
      f32x4 acc3 = *(const f32x4*)(gxp + 3 * 2560);
      // h fragments
      const unsigned short* hb = hB[p];
      const short8 ah0 = *(const short8*)&hb[l15 * 128 + (((0 * 4 + lq) ^ (l15 & 7)) * 8)];
      const short8 ah1 = *(const short8*)&hb[l15 * 128 + (((1 * 4 + lq) ^ (l15 & 7)) * 8)];
      const short8 ah2 = *(const short8*)&hb[l15 * 128 + (((2 * 4 + lq) ^ (l15 & 7)) * 8)];
      const short8 ah3 = *(const short8*)&hb[l15 * 128 + (((3 * 4 + lq) ^ (l15 & 7)) * 8)];
      acc0 = MFMA(ah0, FB[0],  acc0, 0, 0, 0);
      acc1 = MFMA(ah0, FB[4],  acc1, 0, 0, 0);
      acc2 = MFMA(ah0, FB[8],  acc2, 0, 0, 0);
      acc3 = MFMA(ah0, FB[12], acc3, 0, 0, 0);
      acc0 = MFMA(ah1, FB[1],  acc0, 0, 0, 0);
      acc1 = MFMA(ah1, FB[5],  acc1, 0, 0, 0);
      acc2 = MFMA(ah1, FB[9],  acc2, 0, 0, 0);
      acc3 = MFMA(ah1, FB[13], acc3, 0, 0, 0);
      acc0 = MFMA(ah2, FB[2],  acc0, 0, 0, 0);
      acc1 = MFMA(ah2, FB[6],  acc1, 0, 0, 0);
      acc2 = MFMA(ah2, FB[10], acc2, 0, 0, 0);
      acc3 = MFMA(ah2, FB[14], acc3, 0, 0, 0);
      acc0 = MFMA(ah3, FB[3],  acc0, 0, 0, 0);
      acc1 = MFMA(ah3, FB[7],  acc1, 0, 0, 0);
      acc2 = MFMA(ah3, FB[11], acc2, 0, 0, 0);
      acc3 = MFMA(ah3, FB[15], acc3, 0, 0, 0);

      // EW (register-local, 4 cells) -> h_{t+1}
      unsigned short* hbW = hB[p ^ 1];
      {
        f32x2 iv = {acc0[0], acc0[1]}, fv = {acc1[0], acc1[1]};
        f32x2 gv = {acc2[0], acc2[1]}, ov = {acc3[0], acc3[1]};
        f32x2 h01 = ewpair(iv, fv, gv, ov, c01);
        hbW[hw[0]] = f2bf(h01[0]);
        hbW[hw[1]] = f2bf(h01[1]);
      }
      {
        f32x2 iv = {acc0[2], acc0[3]}, fv = {acc1[2], acc1[3]};
        f32x2 gv = {acc2[2], acc2[3]}, ov = {acc3[2], acc3[3]};
        f32x2 h23 = ewpair(iv, fv, gv, ov, c23);
        hbW[hw[2]] = f2bf(h23[0]);
        hbW[hw[3]] = f2bf(h23[1]);
      }
    } else {
      // spare wave 8: y_{t-1} = h_t @ W_out^T + b_out + x_{t-1}
      if (w == 8) {
        const unsigned short* hb = hB[p];
        const short8 ah0 = *(const short8*)&hb[l15 * 128 + (((0 * 4 + lq) ^ (l15 & 7)) * 8)];
        const short8 ah1 = *(const short8*)&hb[l15 * 128 + (((1 * 4 + lq) ^ (l15 & 7)) * 8)];
        const short8 ah2 = *(const short8*)&hb[l15 * 128 + (((2 * 4 + lq) ^ (l15 & 7)) * 8)];
        const short8 ah3 = *(const short8*)&hb[l15 * 128 + (((3 * 4 + lq) ^ (l15 & 7)) * 8)];
        const int ttm = t ? t - 1 : 0;
        f32x4 accY;
        #pragma unroll
        for (int q = 0; q < 4; ++q)
          accY[q] = (l15 < 2) ? (bout_r + xsT[2 * ttm + l15][lq * 4 + q]) : 0.f;
        const short8 fy0 = *(const short8*)&fyB[(0 * 64 + l) * 8];
        const short8 fy1 = *(const short8*)&fyB[(1 * 64 + l) * 8];
        const short8 fy2 = *(const short8*)&fyB[(2 * 64 + l) * 8];
        const short8 fy3 = *(const short8*)&fyB[(3 * 64 + l) * 8];
        accY = MFMA(ah0, fy0, accY, 0, 0, 0);
        accY = MFMA(ah1, fy1, accY, 0, 0, 0);
        accY = MFMA(ah2, fy2, accY, 0, 0, 0);
        accY = MFMA(ah3, fy3, accY, 0, 0, 0);
        if (t > 0 && l15 < 2) {
          #pragma unroll
          for (int q = 0; q < 4; ++q)
            out[obase + (size_t)(lq * 4 + q) * (2 * T_LEN) + 2 * (t - 1) + l15] = accY[q];
        }
      }
      // spares: gates_x[t+1] = embed_{t+1} @ W_ih^T + bias (each wave = 1 gate)
      if (t < T_LEN - 1) {
        const int pn = (t + 1) & 1;
        const unsigned short* eb = embB[pn];
        const short8 ae0 = *(const short8*)&eb[l15 * 64 + ((lq ^ (l15 & 7)) * 8)];
        const short8 ae1 = *(const short8*)&eb[l15 * 64 + (((4 + lq) ^ (l15 & 7)) * 8)];
        #pragma unroll
        for (int tt = 0; tt < 8; ++tt) {
          f32x4 a = (f32x4){biasC[tt], biasC[tt], biasC[tt], biasC[tt]};
          a = MFMA(ae0, FB[tt * 2 + 0], a, 0, 0, 0);
          a = MFMA(ae1, FB[tt * 2 + 1], a, 0, 0, 0);
          *(f32x4*)&gx[pn][(128 * w4 + 16 * tt + l15) * 20 + lq * 4] = a;
        }
      }
      // embed scalars for t+2 (2 per lane)
      if (t < T_LEN - 2) {
        #pragma unroll
        for (int j = 0; j < 2; ++j) {
          const int s = w4 * 64 + l + j * 256;
          const int r = s >> 5, e0 = (s & 31) * 2;
          const int te = t + 2;
          const float x0 = xsT[2 * te][r], x1 = xsT[2 * te + 1][r];
          float v0 = fmaf(x1, WinS[2 * e0 + 1], fmaf(x0, WinS[2 * e0], binS[e0]));
          float v1 = fmaf(x1, WinS[2 * e0 + 3], fmaf(x0, WinS[2 * e0 + 2], binS[e0 + 1]));
          v0 = v0 > 0.f ? v0 : 0.f; v1 = v1 > 0.f ? v1 : 0.f;
          const int ei = r * 64 + (((e0 >> 3) ^ (r & 7)) * 8) + (e0 & 7);
          *(unsigned*)&embB[t & 1][ei] = (unsigned)f2bf(v0) | ((unsigned)f2bf(v1) << 16);
        }
      }
    }
    __syncthreads();   // the ONE barrier per step
  }

  // epilogue: y_255 = h_256 @ W_out^T + b_out + x_255 ; h_256 is in hB[0]
  if (w == 8) {
    const unsigned short* hb = hB[0];
    const short8 ah0 = *(const short8*)&hb[l15 * 128 + (((0 * 4 + lq) ^ (l15 & 7)) * 8)];
    const short8 ah1 = *(const short8*)&hb[l15 * 128 + (((1 * 4 + lq) ^ (l15 & 7)) * 8)];
    const short8 ah2 = *(const short8*)&hb[l15 * 128 + (((2 * 4 + lq) ^ (l15 & 7)) * 8)];
    const short8 ah3 = *(const short8*)&hb[l15 * 128 + (((3 * 4 + lq) ^ (l15 & 7)) * 8)];
    f32x4 accY;
    #pragma unroll
    for (int q = 0; q < 4; ++q)
      accY[q] = (l15 < 2) ? (bout_r + xsT[2 * 255 + l15][lq * 4 + q]) : 0.f;
    const short8 fy0 = *(const short8*)&fyB[(0 * 64 + l) * 8];
    const short8 fy1 = *(const short8*)&fyB[(1 * 64 + l) * 8];
    const short8 fy2 = *(const short8*)&fyB[(2 * 64 + l) * 8];
    const short8 fy3 = *(const short8*)&fyB[(3 * 64 + l) * 8];
    accY = MFMA(ah0, fy0, accY, 0, 0, 0);
    accY = MFMA(ah1, fy1, accY, 0, 0, 0);
    accY = MFMA(ah2, fy2, accY, 0, 0, 0);
    accY = MFMA(ah3, fy3, accY, 0, 0, 0);
    if (l15 < 2) {
      #pragma unroll
      for (int q = 0; q < 4; ++q)
        out[obase + (size_t)(lq * 4 + q) * (2 * T_LEN) + 2 * 255 + l15] = accY[q];
    }
  }
}

extern "C" void kernel_launch(void* const* d_in, const int* in_sizes, int n_in,
                              void* d_out, int out_size, void* d_ws, size_t ws_size,
                              hipStream_t stream) {
  const float* x     = (const float*)d_in[0];
  const float* W_in  = (const float*)d_in[1];
  const float* b_in  = (const float*)d_in[2];
  const float* W_ih  = (const float*)d_in[3];
  const float* W_hh  = (const float*)d_in[4];
  const float* b_ih  = (const float*)d_in[5];
  const float* b_hh  = (const float*)d_in[6];
  const float* W_out = (const float*)d_in[7];
  const float* b_out = (const float*)d_in[8];
  float* out = (float*)d_out;

  lstm_persist<<<dim3(256), dim3(768), 0, stream>>>(
      x, W_in, b_in, W_ih, W_hh, b_ih, b_hh, W_out, b_out, out);
}